// Round 1
// baseline (134.467 us; speedup 1.0000x reference)
//
#include <hip/hip_runtime.h>
#include <hip/hip_bf16.h>

typedef __attribute__((ext_vector_type(8))) short bf16x8;
typedef __attribute__((ext_vector_type(4))) float f32x4;
typedef __attribute__((ext_vector_type(8))) unsigned short u16x8;
typedef __attribute__((ext_vector_type(4))) unsigned short u16x4;

__device__ __forceinline__ unsigned short f2bf_rtne(float f) {
    unsigned int u = __float_as_uint(f);
    u += 0x7FFFu + ((u >> 16) & 1u);
    return (unsigned short)(u >> 16);
}

__device__ __forceinline__ void gl2lds16(const void* g, void* l) {
    __builtin_amdgcn_global_load_lds((const __attribute__((address_space(1))) void*)g,
                                     (__attribute__((address_space(3))) void*)l, 16, 0, 0);
}

// ---------------- f32 -> bf16 convert (vectorized, 8 elems/thread/iter) ----------------
__global__ void cvt_f32_bf16(const float* __restrict__ in, unsigned short* __restrict__ out, int n8) {
    int i = blockIdx.x * blockDim.x + threadIdx.x;
    int stride = gridDim.x * blockDim.x;
    for (; i < n8; i += stride) {
        const float4* p = (const float4*)in + (size_t)i * 2;
        float4 v0 = p[0];
        float4 v1 = p[1];
        u16x8 r;
        r[0] = f2bf_rtne(v0.x); r[1] = f2bf_rtne(v0.y); r[2] = f2bf_rtne(v0.z); r[3] = f2bf_rtne(v0.w);
        r[4] = f2bf_rtne(v1.x); r[5] = f2bf_rtne(v1.y); r[6] = f2bf_rtne(v1.z); r[7] = f2bf_rtne(v1.w);
        *((u16x8*)out + i) = r;
    }
}

// ---------------- weight -> {w_bf16, hash_weight_bf16} ----------------
// hw(w) = sum_i softmax_i(T*(a1_i*w + a2_i*w^2 + a0_i)) * v_i  (elementwise in w)
#define NB 16
__global__ void hash_prep(const float* __restrict__ w,
                          const float* __restrict__ a0, const float* __restrict__ a1,
                          const float* __restrict__ a2, const float* __restrict__ vals,
                          unsigned short* __restrict__ wbf, unsigned short* __restrict__ hwbf,
                          int n4) {
    float A0[NB], A1[NB], A2[NB], V[NB];
#pragma unroll
    for (int b = 0; b < NB; ++b) {
        A0[b] = a0[b] * 100.0f;
        A1[b] = a1[b] * 100.0f;
        A2[b] = a2[b] * 100.0f;
        V[b]  = vals[b];
    }
    int i = blockIdx.x * blockDim.x + threadIdx.x;
    int stride = gridDim.x * blockDim.x;
    for (; i < n4; i += stride) {
        float4 wv = ((const float4*)w)[i];
        float win[4] = {wv.x, wv.y, wv.z, wv.w};
        u16x4 wr, hr;
#pragma unroll
        for (int c = 0; c < 4; ++c) {
            float x = win[c];
            float x2 = x * x;
            float l[NB];
            float mx = -1e30f;
#pragma unroll
            for (int b = 0; b < NB; ++b) {
                l[b] = fmaf(A1[b], x, fmaf(A2[b], x2, A0[b]));
                mx = fmaxf(mx, l[b]);
            }
            float s = 0.0f, acc = 0.0f;
#pragma unroll
            for (int b = 0; b < NB; ++b) {
                float e = __expf(l[b] - mx);
                s += e;
                acc = fmaf(e, V[b], acc);
            }
            wr[c] = f2bf_rtne(x);
            hr[c] = f2bf_rtne(acc / s);
        }
        *((u16x4*)wbf + i)  = wr;
        *((u16x4*)hwbf + i) = hr;
    }
}

// ---------------- bf16 GEMM, C[M][N] = A[M][K] * B[N][K]^T + bias[N] ----------------
// m97 structure: 128x128 tile, BK=32, 4 waves of 64x64, global_load_lds(16B), linear LDS.
// gridDim.z selects (x,W,out) vs (x_hash,hash_w,out_hash).
__global__ __launch_bounds__(256) void gemm_bt_dual(
    const unsigned short* __restrict__ Ax, const unsigned short* __restrict__ Ah,
    const unsigned short* __restrict__ Bw, const unsigned short* __restrict__ Bh,
    const float* __restrict__ bias,
    float* __restrict__ Cx, float* __restrict__ Chh) {
    const int K = 2048, N = 2048;
    const unsigned short* A  = blockIdx.z ? Ah : Ax;
    const unsigned short* Bm = blockIdx.z ? Bh : Bw;
    float* C = blockIdx.z ? Chh : Cx;

    __shared__ unsigned short As[128 * 32];
    __shared__ unsigned short Bs[128 * 32];

    const int tid  = threadIdx.x;
    const int lane = tid & 63;
    const int wid  = tid >> 6;
    const int brow = blockIdx.x;   // M tile (batch rows)
    const int bcol = blockIdx.y;   // N tile

    // staging: each wave stages 2 x 1KB chunks of A and of B per K-step.
    // chunk c covers 16 rows; lane l -> row c*16 + (l>>2), k-offset (l&3)*8 (16B).
    const int c0 = wid * 2, c1 = c0 + 1;
    const int srow = lane >> 2;
    const int skk  = (lane & 3) * 8;
    const unsigned short* gA0 = A  + (size_t)(brow * 128 + c0 * 16 + srow) * K + skk;
    const unsigned short* gA1 = A  + (size_t)(brow * 128 + c1 * 16 + srow) * K + skk;
    const unsigned short* gB0 = Bm + (size_t)(bcol * 128 + c0 * 16 + srow) * K + skk;
    const unsigned short* gB1 = Bm + (size_t)(bcol * 128 + c1 * 16 + srow) * K + skk;
    unsigned short* lA0 = &As[c0 * 512];
    unsigned short* lA1 = &As[c1 * 512];
    unsigned short* lB0 = &Bs[c0 * 512];
    unsigned short* lB1 = &Bs[c1 * 512];

    const int wrow = (wid >> 1) * 64;  // wave's 64x64 quadrant
    const int wcol = (wid & 1) * 64;
    const int fr = lane & 15;          // fragment row/col
    const int fq = lane >> 4;          // k-quad

    f32x4 acc[4][4] = {};

    for (int kt = 0; kt < K; kt += 32) {
        gl2lds16(gA0 + kt, lA0);
        gl2lds16(gA1 + kt, lA1);
        gl2lds16(gB0 + kt, lB0);
        gl2lds16(gB1 + kt, lB1);
        __syncthreads();

        bf16x8 af[4], bfv[4];
#pragma unroll
        for (int m = 0; m < 4; ++m)
            af[m] = *(const bf16x8*)&As[(wrow + m * 16 + fr) * 32 + fq * 8];
#pragma unroll
        for (int n = 0; n < 4; ++n)
            bfv[n] = *(const bf16x8*)&Bs[(wcol + n * 16 + fr) * 32 + fq * 8];
#pragma unroll
        for (int m = 0; m < 4; ++m)
#pragma unroll
            for (int n = 0; n < 4; ++n)
                acc[m][n] = __builtin_amdgcn_mfma_f32_16x16x32_bf16(af[m], bfv[n], acc[m][n], 0, 0, 0);
        __syncthreads();
    }

    // epilogue: D[row][col], row = 4*(lane>>4)+r (M side), col = lane&15 (N side)
#pragma unroll
    for (int n = 0; n < 4; ++n) {
        int col = bcol * 128 + wcol + n * 16 + fr;
        float bv = bias[col];
#pragma unroll
        for (int m = 0; m < 4; ++m) {
            int row0 = brow * 128 + wrow + m * 16 + fq * 4;
#pragma unroll
            for (int r = 0; r < 4; ++r)
                C[(size_t)(row0 + r) * N + col] = acc[m][n][r] + bv;
        }
    }
}

extern "C" void kernel_launch(void* const* d_in, const int* in_sizes, int n_in,
                              void* d_out, int out_size, void* d_ws, size_t ws_size,
                              hipStream_t stream) {
    const float* x    = (const float*)d_in[0];
    const float* xh   = (const float*)d_in[1];
    const float* w    = (const float*)d_in[2];
    const float* bias = (const float*)d_in[3];
    const float* a0   = (const float*)d_in[4];
    const float* a1   = (const float*)d_in[5];
    const float* a2   = (const float*)d_in[6];
    const float* vals = (const float*)d_in[7];

    float* out  = (float*)d_out;
    float* outh = out + (size_t)4096 * 2048;

    char* ws = (char*)d_ws;
    unsigned short* xb  = (unsigned short*)(ws);                              // 16 MB
    unsigned short* xhb = (unsigned short*)(ws + (size_t)16 * 1024 * 1024);   // 16 MB
    unsigned short* wb  = (unsigned short*)(ws + (size_t)32 * 1024 * 1024);   //  8 MB
    unsigned short* hwb = (unsigned short*)(ws + (size_t)40 * 1024 * 1024);   //  8 MB

    cvt_f32_bf16<<<2048, 256, 0, stream>>>(x,  xb,  (4096 * 2048) / 8);
    cvt_f32_bf16<<<2048, 256, 0, stream>>>(xh, xhb, (4096 * 2048) / 8);
    hash_prep<<<2048, 256, 0, stream>>>(w, a0, a1, a2, vals, wb, hwb, (2048 * 2048) / 4);

    dim3 grid(4096 / 128, 2048 / 128, 2);
    gemm_bt_dual<<<grid, 256, 0, stream>>>(xb, xhb, wb, hwb, bias, out, outh);
}

// Round 2
// 102.179 us; speedup vs baseline: 1.3160x; 1.3160x over previous
//
#include <hip/hip_runtime.h>
#include <hip/hip_bf16.h>

typedef __attribute__((ext_vector_type(8))) short bf16x8;
typedef __attribute__((ext_vector_type(4))) float f32x4;
typedef __attribute__((ext_vector_type(8))) unsigned short u16x8;
typedef __attribute__((ext_vector_type(4))) unsigned short u16x4;

__device__ __forceinline__ unsigned short f2bf_rtne(float f) {
    unsigned int u = __float_as_uint(f);
    u += 0x7FFFu + ((u >> 16) & 1u);
    return (unsigned short)(u >> 16);
}

__device__ __forceinline__ void gl2lds16(const void* g, void* l) {
    __builtin_amdgcn_global_load_lds((const __attribute__((address_space(1))) void*)g,
                                     (__attribute__((address_space(3))) void*)l, 16, 0, 0);
}

// ---------------- fused prep: job0/1 = f32->bf16 convert (x, x_hash); job2 = hash_weight ----------------
#define NB 16
__global__ void prep_all(const float* __restrict__ x, const float* __restrict__ xh,
                         const float* __restrict__ w,
                         const float* __restrict__ a0, const float* __restrict__ a1,
                         const float* __restrict__ a2, const float* __restrict__ vals,
                         unsigned short* __restrict__ xb, unsigned short* __restrict__ xhb,
                         unsigned short* __restrict__ wbf, unsigned short* __restrict__ hwbf) {
    const int job = blockIdx.y;
    const int stride = gridDim.x * blockDim.x;
    int i = blockIdx.x * blockDim.x + threadIdx.x;
    if (job < 2) {
        const float* in = job ? xh : x;
        unsigned short* out = job ? xhb : xb;
        const int n8 = (4096 * 2048) / 8;
        for (; i < n8; i += stride) {
            const float4* p = (const float4*)in + (size_t)i * 2;
            float4 v0 = p[0];
            float4 v1 = p[1];
            u16x8 r;
            r[0] = f2bf_rtne(v0.x); r[1] = f2bf_rtne(v0.y); r[2] = f2bf_rtne(v0.z); r[3] = f2bf_rtne(v0.w);
            r[4] = f2bf_rtne(v1.x); r[5] = f2bf_rtne(v1.y); r[6] = f2bf_rtne(v1.z); r[7] = f2bf_rtne(v1.w);
            *((u16x8*)out + i) = r;
        }
    } else {
        float A0[NB], A1[NB], A2[NB], V[NB];
#pragma unroll
        for (int b = 0; b < NB; ++b) {
            A0[b] = a0[b] * 100.0f;
            A1[b] = a1[b] * 100.0f;
            A2[b] = a2[b] * 100.0f;
            V[b]  = vals[b];
        }
        const int n4 = (2048 * 2048) / 4;
        for (; i < n4; i += stride) {
            float4 wv = ((const float4*)w)[i];
            float win[4] = {wv.x, wv.y, wv.z, wv.w};
            u16x4 wr, hr;
#pragma unroll
            for (int c = 0; c < 4; ++c) {
                float xx = win[c];
                float x2 = xx * xx;
                float l[NB];
                float mx = -1e30f;
#pragma unroll
                for (int b = 0; b < NB; ++b) {
                    l[b] = fmaf(A1[b], xx, fmaf(A2[b], x2, A0[b]));
                    mx = fmaxf(mx, l[b]);
                }
                float s = 0.0f, acc = 0.0f;
#pragma unroll
                for (int b = 0; b < NB; ++b) {
                    float e = __expf(l[b] - mx);
                    s += e;
                    acc = fmaf(e, V[b], acc);
                }
                wr[c] = f2bf_rtne(xx);
                hr[c] = f2bf_rtne(acc / s);
            }
            *((u16x4*)wbf + i)  = wr;
            *((u16x4*)hwbf + i) = hr;
        }
    }
}

// ---------------- 256x256-tile 8-phase bf16 GEMM (T2+T3+T4+T5), C = A * B^T + bias ----------------
// BM=BN=256, BK=64, 8 waves (2Mx4N), 128KB LDS double-buffer, K=N=2048, M=4096.
// Swizzle (rule 21): linear LDS dest for global_load_lds; global source granule pre-XOR'd
// with (row&7); ds_read applies the same XOR. Counted vmcnt(4) gates at phases 4/8 only.
__global__ __launch_bounds__(512, 2) void gemm256(
    const unsigned short* __restrict__ Ax, const unsigned short* __restrict__ Ah,
    const unsigned short* __restrict__ Bw, const unsigned short* __restrict__ Bh,
    const float* __restrict__ bias,
    float* __restrict__ Cx, float* __restrict__ Chh) {
    const int K = 2048, N = 2048;

    __shared__ unsigned short lds[65536];  // A: [2][16384], B at +32768: [2][16384]

    const unsigned short* A  = blockIdx.z ? Ah : Ax;
    const unsigned short* Bm = blockIdx.z ? Bh : Bw;
    float* C = blockIdx.z ? Chh : Cx;

    const int tid  = threadIdx.x;
    const int lane = tid & 63;
    const int wid  = tid >> 6;
    const int wr = wid >> 2;          // 0..1 : wave row (128 rows)
    const int wc = wid & 3;           // 0..3 : wave col (64 cols)
    const int fr = lane & 15;
    const int fq = lane >> 4;         // 0..3
    const int brow = blockIdx.x;
    const int bcol = blockIdx.y;

    // staging source (pre-swizzled granule): thread t covers row (t>>3), physical granule (t&7)
    const int srow = tid >> 3;                              // 0..63
    const int sg8  = ((tid & 7) ^ (srow & 7)) * 8;          // logical k-offset (elements)
    const unsigned short* gA = A  + (size_t)(brow * 256 + srow) * K + sg8;
    const unsigned short* gB = Bm + (size_t)(bcol * 256 + srow) * K + sg8;
    const int wbase = wid * 512;                            // wave-uniform LDS base (ushorts)

    // ds_read swizzled granule offsets (ushorts): granule (kk*4+fq) ^ (fr&7)
    const int g0 = (fq ^ (fr & 7)) * 8;   // kk=0
    const int g1 = g0 ^ 32;               // kk=1 (granule ^4 -> ushort ^32)

#define STAGE_A(buf, h, j) {                                                    \
    const unsigned short* _g = gA + (size_t)((h) * 128) * K + (j) * 64;         \
    gl2lds16(_g,                  lds + (buf) * 16384 + (h) * 8192 + wbase);    \
    gl2lds16(_g + (size_t)64 * K, lds + (buf) * 16384 + (h) * 8192 + 4096 + wbase); }
#define STAGE_B(buf, h, j) {                                                    \
    const unsigned short* _g = gB + (size_t)((h) * 128) * K + (j) * 64;         \
    gl2lds16(_g,                  lds + 32768 + (buf) * 16384 + (h) * 8192 + wbase); \
    gl2lds16(_g + (size_t)64 * K, lds + 32768 + (buf) * 16384 + (h) * 8192 + 4096 + wbase); }

#define LDA(dst, buf, mblk) {                                                   \
    const unsigned short* _p = lds + (buf) * 16384 + (wr * 128 + (mblk) * 16 + fr) * 64; \
    dst[0] = *(const bf16x8*)(_p + g0);                                         \
    dst[1] = *(const bf16x8*)(_p + g1); }
#define LDB(dst, buf, nblk) {                                                   \
    const unsigned short* _p = lds + 32768 + (buf) * 16384 + (wc * 64 + (nblk) * 16 + fr) * 64; \
    dst[0] = *(const bf16x8*)(_p + g0);                                         \
    dst[1] = *(const bf16x8*)(_p + g1); }

#define MM(mi, n, kk, AF) acc[mi][n] = __builtin_amdgcn_mfma_f32_16x16x32_bf16(AF[kk], bfr[n][kk], acc[mi][n], 0, 0, 0)

#define PHASE(q, buf, STG, GATE) {                                              \
    if ((q) == 0) {                                                             \
        LDB(bfr[0], buf, 0); LDB(bfr[1], buf, 1);                               \
        LDB(bfr[2], buf, 2); LDB(bfr[3], buf, 3);                               \
    }                                                                           \
    LDA(af0, buf, 2 * (q)); LDA(af1, buf, 2 * (q) + 1);                         \
    STG;                                                                        \
    __builtin_amdgcn_s_barrier();                                               \
    asm volatile("s_waitcnt lgkmcnt(0)" ::: "memory");                          \
    __builtin_amdgcn_s_setprio(1);                                              \
    MM(2*(q),0,0,af0); MM(2*(q),0,1,af0); MM(2*(q)+1,0,0,af1); MM(2*(q)+1,0,1,af1); \
    MM(2*(q),1,0,af0); MM(2*(q),1,1,af0); MM(2*(q)+1,1,0,af1); MM(2*(q)+1,1,1,af1); \
    MM(2*(q),2,0,af0); MM(2*(q),2,1,af0); MM(2*(q)+1,2,0,af1); MM(2*(q)+1,2,1,af1); \
    MM(2*(q),3,0,af0); MM(2*(q),3,1,af0); MM(2*(q)+1,3,0,af1); MM(2*(q)+1,3,1,af1); \
    __builtin_amdgcn_s_setprio(0);                                              \
    GATE;                                                                       \
    __builtin_amdgcn_s_barrier(); }

    // prologue: A(0), B(0), B(1) = 12 loads/thread; keep B(1) (4 loads) in flight
    STAGE_A(0, 0, 0); STAGE_A(0, 1, 0);
    STAGE_B(0, 0, 0); STAGE_B(0, 1, 0);
    STAGE_B(1, 0, 1); STAGE_B(1, 1, 1);
    asm volatile("s_waitcnt vmcnt(4)" ::: "memory");
    __builtin_amdgcn_s_barrier();

    f32x4 acc[8][4] = {};
    bf16x8 bfr[4][2], af0[2], af1[2];

    // steady state: tiles 2t (buf0, phases 1-4) and 2t+1 (buf1, phases 5-8)
    // stages: P1:A0(2t+1) P2:A1(2t+1) P3:B0(2t+2) P4:B1(2t+2)+gate
    //         P5:A0(2t+2) P6:A1(2t+2) P7:B0(2t+3) P8:B1(2t+3)+gate
#pragma unroll 1
    for (int t = 0; t < 15; ++t) {
        const int j1 = 2 * t + 1, j2 = 2 * t + 2, j3 = 2 * t + 3;
        PHASE(0, 0, STAGE_A(1, 0, j1), );
        PHASE(1, 0, STAGE_A(1, 1, j1), );
        PHASE(2, 0, STAGE_B(0, 0, j2), );
        PHASE(3, 0, STAGE_B(0, 1, j2), asm volatile("s_waitcnt vmcnt(4)" ::: "memory"));
        PHASE(0, 1, STAGE_A(0, 0, j2), );
        PHASE(1, 1, STAGE_A(0, 1, j2), );
        PHASE(2, 1, STAGE_B(1, 0, j3), );
        PHASE(3, 1, STAGE_B(1, 1, j3), asm volatile("s_waitcnt vmcnt(4)" ::: "memory"));
    }
    // tail: tiles 30 (buf0), 31 (buf1); A(31) staged here, B(31) staged at t=14
    PHASE(0, 0, STAGE_A(1, 0, 31), );
    PHASE(1, 0, STAGE_A(1, 1, 31), );
    PHASE(2, 0, , );
    PHASE(3, 0, , asm volatile("s_waitcnt vmcnt(0)" ::: "memory"));
    PHASE(0, 1, , );
    PHASE(1, 1, , );
    PHASE(2, 1, , );
    PHASE(3, 1, , );

    // epilogue: C[row][col] += bias; row = m*16 + fq*4 + r, col = n*16 + fr (verified mapping)
#pragma unroll
    for (int n = 0; n < 4; ++n) {
        const int col = bcol * 256 + wc * 64 + n * 16 + fr;
        const float bv = bias[col];
#pragma unroll
        for (int m = 0; m < 8; ++m) {
            const int row0 = brow * 256 + wr * 128 + m * 16 + fq * 4;
#pragma unroll
            for (int r = 0; r < 4; ++r)
                C[(size_t)(row0 + r) * N + col] = acc[m][n][r] + bv;
        }
    }
#undef STAGE_A
#undef STAGE_B
#undef LDA
#undef LDB
#undef MM
#undef PHASE
}

extern "C" void kernel_launch(void* const* d_in, const int* in_sizes, int n_in,
                              void* d_out, int out_size, void* d_ws, size_t ws_size,
                              hipStream_t stream) {
    const float* x    = (const float*)d_in[0];
    const float* xh   = (const float*)d_in[1];
    const float* w    = (const float*)d_in[2];
    const float* bias = (const float*)d_in[3];
    const float* a0   = (const float*)d_in[4];
    const float* a1   = (const float*)d_in[5];
    const float* a2   = (const float*)d_in[6];
    const float* vals = (const float*)d_in[7];

    float* out  = (float*)d_out;
    float* outh = out + (size_t)4096 * 2048;

    char* ws = (char*)d_ws;
    unsigned short* xb  = (unsigned short*)(ws);                              // 16 MB
    unsigned short* xhb = (unsigned short*)(ws + (size_t)16 * 1024 * 1024);   // 16 MB
    unsigned short* wb  = (unsigned short*)(ws + (size_t)32 * 1024 * 1024);   //  8 MB
    unsigned short* hwb = (unsigned short*)(ws + (size_t)40 * 1024 * 1024);   //  8 MB

    prep_all<<<dim3(1024, 3), 256, 0, stream>>>(x, xh, w, a0, a1, a2, vals, xb, xhb, wb, hwb);

    dim3 grid(4096 / 256, 2048 / 256, 2);
    gemm256<<<grid, 512, 0, stream>>>(xb, xhb, wb, hwb, bias, out, outh);
}